// Round 1
// baseline (3772.659 us; speedup 1.0000x reference)
//
#include <hip/hip_runtime.h>

#define N_NODES 50000
#define IN_F    128
#define HID_F   128
#define OUT_F   64
#define E_EDGES 800000

// ---------------- Dense GEMM: C[M,NF] = act(A)[M,K] @ W[K,NF] ----------------
// 16x16 tile, one output per thread. RELU_A applies relu to A elements on load.
template<int K, int NF, bool RELU_A>
__global__ void gemm_kernel(const float* __restrict__ A,
                            const float* __restrict__ W,
                            float* __restrict__ C, int M) {
    __shared__ float As[16][17];
    __shared__ float Ws[16][17];
    const int tx = threadIdx.x, ty = threadIdx.y;
    const int row = blockIdx.y * 16 + ty;
    const int col = blockIdx.x * 16 + tx;
    float acc = 0.f;
    for (int k0 = 0; k0 < K; k0 += 16) {
        float a = (row < M) ? A[(long)row * K + k0 + tx] : 0.f;
        if (RELU_A) a = a > 0.f ? a : 0.f;
        As[ty][tx] = a;
        Ws[ty][tx] = W[(long)(k0 + ty) * NF + col];
        __syncthreads();
#pragma unroll
        for (int kk = 0; kk < 16; ++kk)
            acc += As[ty][kk] * Ws[kk][tx];
        __syncthreads();
    }
    if (row < M) C[(long)row * NF + col] = acc;
}

// ---------------- Init: out[i*F + f] = bias[f] ----------------
template<int F>
__global__ void init_bias_kernel(float* __restrict__ out,
                                 const float* __restrict__ bias, int total) {
    int tid = blockIdx.x * blockDim.x + threadIdx.x;
    if (tid < total) out[tid] = bias[tid & (F - 1)];
}

// ---------------- Edge scatter: out[row[e]] += val[e] * sup[col[e]] ----------
// One thread handles 4 consecutive features of one edge.
template<int F>
__global__ void scatter_kernel(const int* __restrict__ rowi,
                               const int* __restrict__ coli,
                               const float* __restrict__ val,
                               const float* __restrict__ sup,
                               float* __restrict__ out, int E) {
    constexpr int G = F / 4;  // float4 groups per edge
    long tid = (long)blockIdx.x * blockDim.x + threadIdx.x;
    int e = (int)(tid / G);
    int g = (int)(tid % G);
    if (e >= E) return;
    const int r = rowi[e];
    const int c = coli[e];
    const float v = val[e];
    const float4 s = *(const float4*)(sup + (long)c * F + g * 4);
    float* o = out + (long)r * F + g * 4;
    atomicAdd(o + 0, v * s.x);
    atomicAdd(o + 1, v * s.y);
    atomicAdd(o + 2, v * s.z);
    atomicAdd(o + 3, v * s.w);
}

extern "C" void kernel_launch(void* const* d_in, const int* in_sizes, int n_in,
                              void* d_out, int out_size, void* d_ws, size_t ws_size,
                              hipStream_t stream) {
    const float* x    = (const float*)d_in[0];
    const int*   row0 = (const int*)d_in[1];
    const int*   col0 = (const int*)d_in[2];
    const float* val0 = (const float*)d_in[3];
    const int*   row1 = (const int*)d_in[4];
    const int*   col1 = (const int*)d_in[5];
    const float* val1 = (const float*)d_in[6];
    const float* W0   = (const float*)d_in[7];
    const float* b0   = (const float*)d_in[8];
    const float* W1   = (const float*)d_in[9];
    const float* b1   = (const float*)d_in[10];
    float* out = (float*)d_out;

    // Workspace layout (fp32):
    //   support0: N*HID_F  (25.6 MB)
    //   h:        N*HID_F  (25.6 MB)
    //   support1: N*OUT_F  (12.8 MB)
    float* support0 = (float*)d_ws;
    float* h        = support0 + (long)N_NODES * HID_F;
    float* support1 = h + (long)N_NODES * HID_F;

    const int M = N_NODES;

    // ---- Layer 0 ----
    // support0 = x @ W0
    {
        dim3 grid(HID_F / 16, (M + 15) / 16);
        dim3 block(16, 16);
        gemm_kernel<IN_F, HID_F, false><<<grid, block, 0, stream>>>(x, W0, support0, M);
    }
    // h = broadcast(b0)
    {
        int total = M * HID_F;
        init_bias_kernel<HID_F><<<(total + 255) / 256, 256, 0, stream>>>(h, b0, total);
    }
    // h[row0] += val0 * support0[col0]
    {
        long threads = (long)E_EDGES * (HID_F / 4);
        scatter_kernel<HID_F><<<(threads + 255) / 256, 256, 0, stream>>>(
            row0, col0, val0, support0, h, E_EDGES);
    }

    // ---- Layer 1 ----
    // support1 = relu(h) @ W1   (relu fused into A load)
    {
        dim3 grid(OUT_F / 16, (M + 15) / 16);
        dim3 block(16, 16);
        gemm_kernel<HID_F, OUT_F, true><<<grid, block, 0, stream>>>(h, W1, support1, M);
    }
    // out = broadcast(b1)
    {
        int total = M * OUT_F;
        init_bias_kernel<OUT_F><<<(total + 255) / 256, 256, 0, stream>>>(out, b1, total);
    }
    // out[row1] += val1 * support1[col1]
    {
        long threads = (long)E_EDGES * (OUT_F / 4);
        scatter_kernel<OUT_F><<<(threads + 255) / 256, 256, 0, stream>>>(
            row1, col1, val1, support1, out, E_EDGES);
    }
}

// Round 2
// 676.663 us; speedup vs baseline: 5.5754x; 5.5754x over previous
//
#include <hip/hip_runtime.h>

#define N_NODES 50000
#define IN_F    128
#define HID_F   128
#define OUT_F   64
#define E_EDGES 800000

__device__ __forceinline__ float relu_f(float x) { return x > 0.f ? x : 0.f; }

// ---------------- Dense GEMM: C[M,NF] = act(A)[M,K] @ W[K,NF] ----------------
// 64x64 tile, 256 threads, 4x4 outputs per thread, K-step 16.
template<int K, int NF, bool RELU_A>
__global__ __launch_bounds__(256) void gemm64_kernel(const float* __restrict__ A,
                                                     const float* __restrict__ W,
                                                     float* __restrict__ C, int M) {
    __shared__ float As[16][68];  // [kk][row], stride 68 keeps float4 alignment
    __shared__ float Ws[16][68];  // [kk][col]
    const int tid = threadIdx.x;
    const int tx = tid & 15, ty = tid >> 4;
    const int row0 = blockIdx.y * 64;
    const int col0 = blockIdx.x * 64;
    float acc[4][4] = {};
    for (int k0 = 0; k0 < K; k0 += 16) {
        // A tile: 64 rows x 16 k. Thread loads float4 along k.
        {
            const int r  = tid >> 2;          // 0..63
            const int kk = (tid & 3) << 2;    // 0,4,8,12
            const int grow = row0 + r;
            float4 a = make_float4(0.f, 0.f, 0.f, 0.f);
            if (grow < M) a = *(const float4*)(A + (long)grow * K + k0 + kk);
            if (RELU_A) { a.x = relu_f(a.x); a.y = relu_f(a.y); a.z = relu_f(a.z); a.w = relu_f(a.w); }
            As[kk + 0][r] = a.x; As[kk + 1][r] = a.y; As[kk + 2][r] = a.z; As[kk + 3][r] = a.w;
        }
        // W tile: 16 k x 64 cols. Thread loads float4 along cols.
        {
            const int kr = tid >> 4;          // 0..15
            const int c  = (tid & 15) << 2;   // 0..60
            float4 w = *(const float4*)(W + (long)(k0 + kr) * NF + col0 + c);
            *(float4*)&Ws[kr][c] = w;
        }
        __syncthreads();
#pragma unroll
        for (int kk = 0; kk < 16; ++kk) {
            float4 a = *(float4*)&As[kk][ty << 2];
            float4 w = *(float4*)&Ws[kk][tx << 2];
            acc[0][0] += a.x * w.x; acc[0][1] += a.x * w.y; acc[0][2] += a.x * w.z; acc[0][3] += a.x * w.w;
            acc[1][0] += a.y * w.x; acc[1][1] += a.y * w.y; acc[1][2] += a.y * w.z; acc[1][3] += a.y * w.w;
            acc[2][0] += a.z * w.x; acc[2][1] += a.z * w.y; acc[2][2] += a.z * w.z; acc[2][3] += a.z * w.w;
            acc[3][0] += a.w * w.x; acc[3][1] += a.w * w.y; acc[3][2] += a.w * w.z; acc[3][3] += a.w * w.w;
        }
        __syncthreads();
    }
#pragma unroll
    for (int i = 0; i < 4; ++i) {
        const int grow = row0 + (ty << 2) + i;
        if (grow < M) {
            float4 o = make_float4(acc[i][0], acc[i][1], acc[i][2], acc[i][3]);
            *(float4*)(C + (long)grow * NF + col0 + (tx << 2)) = o;
        }
    }
}

// ---------------- CSR build ----------------
__global__ void zero_int_kernel(int* __restrict__ p, int n) {
    int tid = blockIdx.x * blockDim.x + threadIdx.x;
    if (tid < n) p[tid] = 0;
}

__global__ void hist_kernel(const int* __restrict__ rowi, int* __restrict__ deg, int E) {
    int tid = blockIdx.x * blockDim.x + threadIdx.x;
    if (tid < E) atomicAdd(&deg[rowi[tid]], 1);
}

// Single-block exclusive scan: deg[0..n) -> rowptr[0..n], rowptr[n] = total.
__global__ __launch_bounds__(1024) void scan_kernel(const int* __restrict__ deg,
                                                    int* __restrict__ rowptr, int n) {
    __shared__ int sums[1024];
    const int t = threadIdx.x;
    const int seg = (n + 1023) / 1024;
    const int base = t * seg;
    int s = 0;
    for (int i = 0; i < seg; ++i) {
        int idx = base + i;
        if (idx < n) s += deg[idx];
    }
    sums[t] = s;
    __syncthreads();
    // Hillis-Steele inclusive scan over 1024 partials
    for (int off = 1; off < 1024; off <<= 1) {
        int v = (t >= off) ? sums[t - off] : 0;
        __syncthreads();
        sums[t] += v;
        __syncthreads();
    }
    int run = (t == 0) ? 0 : sums[t - 1];
    for (int i = 0; i < seg; ++i) {
        int idx = base + i;
        if (idx < n) { rowptr[idx] = run; run += deg[idx]; }
    }
    if (t == 1023) rowptr[n] = sums[1023];
}

__global__ void fill_kernel(const int* __restrict__ rowi, const int* __restrict__ coli,
                            const float* __restrict__ vali, const int* __restrict__ rowptr,
                            int* __restrict__ fillc, int* __restrict__ ccol,
                            float* __restrict__ cval, int E) {
    int tid = blockIdx.x * blockDim.x + threadIdx.x;
    if (tid < E) {
        int r = rowi[tid];
        int pos = rowptr[r] + atomicAdd(&fillc[r], 1);
        ccol[pos] = coli[tid];
        cval[pos] = vali[tid];
    }
}

// ---------------- CSR SpMM: out[r] = bias + sum_e val[e] * sup[col[e]] -------
// One wave (64 lanes) per row; each lane handles VEC features. F = 64*VEC.
template<int F, int VEC>
__global__ __launch_bounds__(256) void spmm_kernel(const int* __restrict__ rowptr,
                                                   const int* __restrict__ cols,
                                                   const float* __restrict__ vals,
                                                   const float* __restrict__ sup,
                                                   const float* __restrict__ bias,
                                                   float* __restrict__ out, int n) {
    static_assert(F == 64 * VEC, "one wave per row");
    const int wave = threadIdx.x >> 6;
    const int lane = threadIdx.x & 63;
    const int r = blockIdx.x * 4 + wave;
    if (r >= n) return;
    const int start = rowptr[r];
    const int end   = rowptr[r + 1];
    const int f0 = lane * VEC;
    float acc[VEC];
#pragma unroll
    for (int i = 0; i < VEC; ++i) acc[i] = bias[f0 + i];
    for (int e = start; e < end; ++e) {
        const int c   = cols[e];
        const float v = vals[e];
        const float* sp = sup + (long)c * F + f0;
        if constexpr (VEC == 2) {
            float2 s = *(const float2*)sp;
            acc[0] += v * s.x;
            acc[1] += v * s.y;
        } else {
            acc[0] += v * sp[0];
        }
    }
    float* op = out + (long)r * F + f0;
    if constexpr (VEC == 2) {
        *(float2*)op = make_float2(acc[0], acc[1]);
    } else {
        op[0] = acc[0];
    }
}

extern "C" void kernel_launch(void* const* d_in, const int* in_sizes, int n_in,
                              void* d_out, int out_size, void* d_ws, size_t ws_size,
                              hipStream_t stream) {
    const float* x    = (const float*)d_in[0];
    const int*   row0 = (const int*)d_in[1];
    const int*   col0 = (const int*)d_in[2];
    const float* val0 = (const float*)d_in[3];
    const int*   row1 = (const int*)d_in[4];
    const int*   col1 = (const int*)d_in[5];
    const float* val1 = (const float*)d_in[6];
    const float* W0   = (const float*)d_in[7];
    const float* b0   = (const float*)d_in[8];
    const float* W1   = (const float*)d_in[9];
    const float* b1   = (const float*)d_in[10];
    float* out = (float*)d_out;

    const int M = N_NODES;

    // Workspace layout:
    //   support0: N*128 f32 (25.6 MB) -- reused as support1 (N*64, 12.8 MB)
    //   h:        N*128 f32 (25.6 MB)
    //   rowptr:   N+1 int
    //   deg:      N int   (deg+fill contiguous for one zero pass)
    //   fillc:    N int
    //   csr_col:  E int
    //   csr_val:  E f32
    float* support0 = (float*)d_ws;
    float* h        = support0 + (long)N_NODES * HID_F;
    int*   rowptr   = (int*)(h + (long)N_NODES * HID_F);
    int*   deg      = rowptr + (N_NODES + 1);
    int*   fillc    = deg + N_NODES;
    int*   csr_col  = fillc + N_NODES;
    float* csr_val  = (float*)(csr_col + E_EDGES);
    float* support1 = support0;  // support0 dead after spmm0

    const int ZB = (2 * N_NODES + 255) / 256;
    const int EB = (E_EDGES + 255) / 256;
    const int SPMM_B = (N_NODES + 3) / 4;

    // ---- Layer 0 ----
    {
        dim3 grid(HID_F / 64, (M + 63) / 64);
        gemm64_kernel<IN_F, HID_F, false><<<grid, 256, 0, stream>>>(x, W0, support0, M);
    }
    zero_int_kernel<<<ZB, 256, 0, stream>>>(deg, 2 * N_NODES);  // deg + fillc
    hist_kernel<<<EB, 256, 0, stream>>>(row0, deg, E_EDGES);
    scan_kernel<<<1, 1024, 0, stream>>>(deg, rowptr, N_NODES);
    fill_kernel<<<EB, 256, 0, stream>>>(row0, col0, val0, rowptr, fillc, csr_col, csr_val, E_EDGES);
    spmm_kernel<HID_F, 2><<<SPMM_B, 256, 0, stream>>>(rowptr, csr_col, csr_val,
                                                      support0, b0, h, N_NODES);

    // ---- Layer 1 ----
    {
        dim3 grid(OUT_F / 64, (M + 63) / 64);
        gemm64_kernel<HID_F, OUT_F, true><<<grid, 256, 0, stream>>>(h, W1, support1, M);
    }
    zero_int_kernel<<<ZB, 256, 0, stream>>>(deg, 2 * N_NODES);
    hist_kernel<<<EB, 256, 0, stream>>>(row1, deg, E_EDGES);
    scan_kernel<<<1, 1024, 0, stream>>>(deg, rowptr, N_NODES);
    fill_kernel<<<EB, 256, 0, stream>>>(row1, col1, val1, rowptr, fillc, csr_col, csr_val, E_EDGES);
    spmm_kernel<OUT_F, 1><<<SPMM_B, 256, 0, stream>>>(rowptr, csr_col, csr_val,
                                                      support1, b1, out, N_NODES);
}

// Round 3
// 498.360 us; speedup vs baseline: 7.5702x; 1.3578x over previous
//
#include <hip/hip_runtime.h>

#define N_NODES 50000
#define IN_F    128
#define HID_F   128
#define OUT_F   64
#define E_EDGES 800000

#define SCAN_B 256
#define SCAN_NB ((N_NODES + SCAN_B - 1) / SCAN_B)   // 196

__device__ __forceinline__ float relu_f(float x) { return x > 0.f ? x : 0.f; }

// ---------------- Dense GEMM: C[M,NF] = act(A)[M,K] @ W[K,NF] ----------------
// 64x64 tile, 256 threads, 4x4 outputs per thread, K-step 16.
template<int K, int NF, bool RELU_A>
__global__ __launch_bounds__(256) void gemm64_kernel(const float* __restrict__ A,
                                                     const float* __restrict__ W,
                                                     float* __restrict__ C, int M) {
    __shared__ float As[16][68];
    __shared__ float Ws[16][68];
    const int tid = threadIdx.x;
    const int tx = tid & 15, ty = tid >> 4;
    const int row0 = blockIdx.y * 64;
    const int col0 = blockIdx.x * 64;
    float acc[4][4] = {};
    for (int k0 = 0; k0 < K; k0 += 16) {
        {
            const int r  = tid >> 2;
            const int kk = (tid & 3) << 2;
            const int grow = row0 + r;
            float4 a = make_float4(0.f, 0.f, 0.f, 0.f);
            if (grow < M) a = *(const float4*)(A + (long)grow * K + k0 + kk);
            if (RELU_A) { a.x = relu_f(a.x); a.y = relu_f(a.y); a.z = relu_f(a.z); a.w = relu_f(a.w); }
            As[kk + 0][r] = a.x; As[kk + 1][r] = a.y; As[kk + 2][r] = a.z; As[kk + 3][r] = a.w;
        }
        {
            const int kr = tid >> 4;
            const int c  = (tid & 15) << 2;
            float4 w = *(const float4*)(W + (long)(k0 + kr) * NF + col0 + c);
            *(float4*)&Ws[kr][c] = w;
        }
        __syncthreads();
#pragma unroll
        for (int kk = 0; kk < 16; ++kk) {
            float4 a = *(float4*)&As[kk][ty << 2];
            float4 w = *(float4*)&Ws[kk][tx << 2];
            acc[0][0] += a.x * w.x; acc[0][1] += a.x * w.y; acc[0][2] += a.x * w.z; acc[0][3] += a.x * w.w;
            acc[1][0] += a.y * w.x; acc[1][1] += a.y * w.y; acc[1][2] += a.y * w.z; acc[1][3] += a.y * w.w;
            acc[2][0] += a.z * w.x; acc[2][1] += a.z * w.y; acc[2][2] += a.z * w.z; acc[2][3] += a.z * w.w;
            acc[3][0] += a.w * w.x; acc[3][1] += a.w * w.y; acc[3][2] += a.w * w.z; acc[3][3] += a.w * w.w;
        }
        __syncthreads();
    }
#pragma unroll
    for (int i = 0; i < 4; ++i) {
        const int grow = row0 + (ty << 2) + i;
        if (grow < M) {
            float4 o = make_float4(acc[i][0], acc[i][1], acc[i][2], acc[i][3]);
            *(float4*)(C + (long)grow * NF + col0 + (tx << 2)) = o;
        }
    }
}

// ---------------- CSR build ----------------
__global__ void zero_int_kernel(int* __restrict__ p, int n) {
    int tid = blockIdx.x * blockDim.x + threadIdx.x;
    if (tid < n) p[tid] = 0;
}

__global__ void hist_kernel(const int* __restrict__ rowi, int* __restrict__ deg, int E) {
    int tid = blockIdx.x * blockDim.x + threadIdx.x;
    if (tid < E) atomicAdd(&deg[rowi[tid]], 1);
}

// Phase A: per-block sums. grid = SCAN_NB, block = 256.
__global__ __launch_bounds__(256) void scan_sum_kernel(const int* __restrict__ deg,
                                                       int* __restrict__ partials, int n) {
    __shared__ int red[4];
    const int idx = blockIdx.x * SCAN_B + threadIdx.x;
    int v = (idx < n) ? deg[idx] : 0;
#pragma unroll
    for (int off = 32; off > 0; off >>= 1) v += __shfl_down(v, off, 64);
    const int lane = threadIdx.x & 63, wave = threadIdx.x >> 6;
    if (lane == 0) red[wave] = v;
    __syncthreads();
    if (threadIdx.x == 0)
        partials[blockIdx.x] = red[0] + red[1] + red[2] + red[3];
}

// Phase B: exclusive scan of partials in one block (nb <= 256).
__global__ __launch_bounds__(256) void scan_partials_kernel(int* __restrict__ partials, int nb) {
    __shared__ int s[SCAN_B];
    const int t = threadIdx.x;
    s[t] = (t < nb) ? partials[t] : 0;
    __syncthreads();
    for (int off = 1; off < SCAN_B; off <<= 1) {
        int v = (t >= off) ? s[t - off] : 0;
        __syncthreads();
        s[t] += v;
        __syncthreads();
    }
    if (t < nb) partials[t] = (t == 0) ? 0 : s[t - 1];  // exclusive
}

// Phase C: per-block exclusive scan + offset -> rowptr. Last element writes rowptr[n].
__global__ __launch_bounds__(256) void scan_final_kernel(const int* __restrict__ deg,
                                                         const int* __restrict__ partials,
                                                         int* __restrict__ rowptr, int n) {
    __shared__ int s[SCAN_B];
    const int t = threadIdx.x;
    const int idx = blockIdx.x * SCAN_B + t;
    const int v0 = (idx < n) ? deg[idx] : 0;
    s[t] = v0;
    __syncthreads();
    for (int off = 1; off < SCAN_B; off <<= 1) {
        int v = (t >= off) ? s[t - off] : 0;
        __syncthreads();
        s[t] += v;
        __syncthreads();
    }
    const int excl = partials[blockIdx.x] + s[t] - v0;
    if (idx < n) {
        rowptr[idx] = excl;
        if (idx == n - 1) rowptr[n] = excl + v0;
    }
}

__global__ void fill_kernel(const int* __restrict__ rowi, const int* __restrict__ coli,
                            const float* __restrict__ vali, const int* __restrict__ rowptr,
                            int* __restrict__ fillc, int* __restrict__ ccol,
                            float* __restrict__ cval, int E) {
    int tid = blockIdx.x * blockDim.x + threadIdx.x;
    if (tid < E) {
        int r = rowi[tid];
        int pos = rowptr[r] + atomicAdd(&fillc[r], 1);
        ccol[pos] = coli[tid];
        cval[pos] = vali[tid];
    }
}

// ---------------- CSR SpMM: out[r] = bias + sum_e val[e] * sup[col[e]] -------
template<int F, int VEC>
__global__ __launch_bounds__(256) void spmm_kernel(const int* __restrict__ rowptr,
                                                   const int* __restrict__ cols,
                                                   const float* __restrict__ vals,
                                                   const float* __restrict__ sup,
                                                   const float* __restrict__ bias,
                                                   float* __restrict__ out, int n) {
    static_assert(F == 64 * VEC, "one wave per row");
    const int wave = threadIdx.x >> 6;
    const int lane = threadIdx.x & 63;
    const int r = blockIdx.x * 4 + wave;
    if (r >= n) return;
    const int start = rowptr[r];
    const int end   = rowptr[r + 1];
    const int f0 = lane * VEC;
    float acc[VEC];
#pragma unroll
    for (int i = 0; i < VEC; ++i) acc[i] = bias[f0 + i];
    for (int e = start; e < end; ++e) {
        const int c   = cols[e];
        const float v = vals[e];
        const float* sp = sup + (long)c * F + f0;
        if constexpr (VEC == 2) {
            float2 s = *(const float2*)sp;
            acc[0] += v * s.x;
            acc[1] += v * s.y;
        } else {
            acc[0] += v * sp[0];
        }
    }
    float* op = out + (long)r * F + f0;
    if constexpr (VEC == 2) {
        *(float2*)op = make_float2(acc[0], acc[1]);
    } else {
        op[0] = acc[0];
    }
}

extern "C" void kernel_launch(void* const* d_in, const int* in_sizes, int n_in,
                              void* d_out, int out_size, void* d_ws, size_t ws_size,
                              hipStream_t stream) {
    const float* x    = (const float*)d_in[0];
    const int*   row0 = (const int*)d_in[1];
    const int*   col0 = (const int*)d_in[2];
    const float* val0 = (const float*)d_in[3];
    const int*   row1 = (const int*)d_in[4];
    const int*   col1 = (const int*)d_in[5];
    const float* val1 = (const float*)d_in[6];
    const float* W0   = (const float*)d_in[7];
    const float* b0   = (const float*)d_in[8];
    const float* W1   = (const float*)d_in[9];
    const float* b1   = (const float*)d_in[10];
    float* out = (float*)d_out;

    const int M = N_NODES;

    float* support0 = (float*)d_ws;
    float* h        = support0 + (long)N_NODES * HID_F;
    int*   rowptr   = (int*)(h + (long)N_NODES * HID_F);
    int*   deg      = rowptr + (N_NODES + 1);
    int*   fillc    = deg + N_NODES;
    int*   partials = fillc + N_NODES;
    int*   csr_col  = partials + SCAN_NB;
    float* csr_val  = (float*)(csr_col + E_EDGES);
    float* support1 = support0;  // support0 dead after spmm0

    const int ZB = (2 * N_NODES + 255) / 256;
    const int EB = (E_EDGES + 255) / 256;
    const int SPMM_B = (N_NODES + 3) / 4;

    // ---- Layer 0 ----
    {
        dim3 grid(HID_F / 64, (M + 63) / 64);
        gemm64_kernel<IN_F, HID_F, false><<<grid, 256, 0, stream>>>(x, W0, support0, M);
    }
    zero_int_kernel<<<ZB, 256, 0, stream>>>(deg, 2 * N_NODES);  // deg + fillc
    hist_kernel<<<EB, 256, 0, stream>>>(row0, deg, E_EDGES);
    scan_sum_kernel<<<SCAN_NB, SCAN_B, 0, stream>>>(deg, partials, N_NODES);
    scan_partials_kernel<<<1, SCAN_B, 0, stream>>>(partials, SCAN_NB);
    scan_final_kernel<<<SCAN_NB, SCAN_B, 0, stream>>>(deg, partials, rowptr, N_NODES);
    fill_kernel<<<EB, 256, 0, stream>>>(row0, col0, val0, rowptr, fillc, csr_col, csr_val, E_EDGES);
    spmm_kernel<HID_F, 2><<<SPMM_B, 256, 0, stream>>>(rowptr, csr_col, csr_val,
                                                      support0, b0, h, N_NODES);

    // ---- Layer 1 ----
    {
        dim3 grid(OUT_F / 64, (M + 63) / 64);
        gemm64_kernel<HID_F, OUT_F, true><<<grid, 256, 0, stream>>>(h, W1, support1, M);
    }
    zero_int_kernel<<<ZB, 256, 0, stream>>>(deg, 2 * N_NODES);
    hist_kernel<<<EB, 256, 0, stream>>>(row1, deg, E_EDGES);
    scan_sum_kernel<<<SCAN_NB, SCAN_B, 0, stream>>>(deg, partials, N_NODES);
    scan_partials_kernel<<<1, SCAN_B, 0, stream>>>(partials, SCAN_NB);
    scan_final_kernel<<<SCAN_NB, SCAN_B, 0, stream>>>(deg, partials, rowptr, N_NODES);
    fill_kernel<<<EB, 256, 0, stream>>>(row1, col1, val1, rowptr, fillc, csr_col, csr_val, E_EDGES);
    spmm_kernel<OUT_F, 1><<<SPMM_B, 256, 0, stream>>>(rowptr, csr_col, csr_val,
                                                      support1, b1, out, N_NODES);
}

// Round 4
// 462.392 us; speedup vs baseline: 8.1590x; 1.0778x over previous
//
#include <hip/hip_runtime.h>
#include <hip/hip_fp16.h>
#include <type_traits>

#define N_NODES 50000
#define IN_F    128
#define HID_F   128
#define OUT_F   64
#define E_EDGES 800000

#define SCAN_B 256
#define SCAN_NB ((N_NODES + SCAN_B - 1) / SCAN_B)   // 196

__device__ __forceinline__ float relu_f(float x) { return x > 0.f ? x : 0.f; }

// ---------------- Dense GEMM: C[M,NF] = act(A)[M,K] @ W[K,NF], C in fp16 -----
// 64x64 tile, 256 threads, 4x4 outputs per thread, K-step 16. fp32 accumulate.
template<int K, int NF, bool RELU_A, typename AT>
__global__ __launch_bounds__(256) void gemm64_kernel(const AT* __restrict__ A,
                                                     const float* __restrict__ W,
                                                     __half* __restrict__ C, int M) {
    __shared__ float As[16][68];
    __shared__ float Ws[16][68];
    const int tid = threadIdx.x;
    const int tx = tid & 15, ty = tid >> 4;
    const int row0 = blockIdx.y * 64;
    const int col0 = blockIdx.x * 64;
    float acc[4][4] = {};
    for (int k0 = 0; k0 < K; k0 += 16) {
        // A tile: 64 rows x 16 k. Thread loads 4 k-elements.
        {
            const int r  = tid >> 2;
            const int kk = (tid & 3) << 2;
            const int grow = row0 + r;
            float a0 = 0.f, a1 = 0.f, a2 = 0.f, a3 = 0.f;
            if (grow < M) {
                if constexpr (std::is_same<AT, float>::value) {
                    float4 a = *(const float4*)(A + (long)grow * K + k0 + kk);
                    a0 = a.x; a1 = a.y; a2 = a.z; a3 = a.w;
                } else {
                    const __half2* p = (const __half2*)(A + (long)grow * K + k0 + kk);
                    float2 x0 = __half22float2(p[0]);
                    float2 x1 = __half22float2(p[1]);
                    a0 = x0.x; a1 = x0.y; a2 = x1.x; a3 = x1.y;
                }
            }
            if (RELU_A) { a0 = relu_f(a0); a1 = relu_f(a1); a2 = relu_f(a2); a3 = relu_f(a3); }
            As[kk + 0][r] = a0; As[kk + 1][r] = a1; As[kk + 2][r] = a2; As[kk + 3][r] = a3;
        }
        // W tile: 16 k x 64 cols.
        {
            const int kr = tid >> 4;
            const int c  = (tid & 15) << 2;
            float4 w = *(const float4*)(W + (long)(k0 + kr) * NF + col0 + c);
            *(float4*)&Ws[kr][c] = w;
        }
        __syncthreads();
#pragma unroll
        for (int kk = 0; kk < 16; ++kk) {
            float4 a = *(float4*)&As[kk][ty << 2];
            float4 w = *(float4*)&Ws[kk][tx << 2];
            acc[0][0] += a.x * w.x; acc[0][1] += a.x * w.y; acc[0][2] += a.x * w.z; acc[0][3] += a.x * w.w;
            acc[1][0] += a.y * w.x; acc[1][1] += a.y * w.y; acc[1][2] += a.y * w.z; acc[1][3] += a.y * w.w;
            acc[2][0] += a.z * w.x; acc[2][1] += a.z * w.y; acc[2][2] += a.z * w.z; acc[2][3] += a.z * w.w;
            acc[3][0] += a.w * w.x; acc[3][1] += a.w * w.y; acc[3][2] += a.w * w.z; acc[3][3] += a.w * w.w;
        }
        __syncthreads();
    }
#pragma unroll
    for (int i = 0; i < 4; ++i) {
        const int grow = row0 + (ty << 2) + i;
        if (grow < M) {
            union { __half2 h2[2]; uint2 u; } p;
            p.h2[0] = __floats2half2_rn(acc[i][0], acc[i][1]);
            p.h2[1] = __floats2half2_rn(acc[i][2], acc[i][3]);
            *(uint2*)(C + (long)grow * NF + col0 + (tx << 2)) = p.u;
        }
    }
}

// ---------------- CSR build (both graphs at once) ----------------
__global__ void zero_int_kernel(int* __restrict__ p, int n) {
    int tid = blockIdx.x * blockDim.x + threadIdx.x;
    if (tid < n) p[tid] = 0;
}

// deg layout: deg0 [0,n), deg1 [n,2n)
__global__ void hist2_kernel(const int* __restrict__ row0, const int* __restrict__ row1,
                             int* __restrict__ deg, int E, int n) {
    int tid = blockIdx.x * blockDim.x + threadIdx.x;
    if (tid < E) atomicAdd(&deg[row0[tid]], 1);
    else if (tid < 2 * E) atomicAdd(&deg[n + row1[tid - E]], 1);
}

// Phase A: per-block sums. grid = (SCAN_NB, 2).
__global__ __launch_bounds__(256) void scan_sum_kernel(const int* __restrict__ deg,
                                                       int* __restrict__ partials, int n) {
    __shared__ int red[4];
    const int* d = deg + (long)blockIdx.y * n;
    int* p = partials + (long)blockIdx.y * SCAN_NB;
    const int idx = blockIdx.x * SCAN_B + threadIdx.x;
    int v = (idx < n) ? d[idx] : 0;
#pragma unroll
    for (int off = 32; off > 0; off >>= 1) v += __shfl_down(v, off, 64);
    const int lane = threadIdx.x & 63, wave = threadIdx.x >> 6;
    if (lane == 0) red[wave] = v;
    __syncthreads();
    if (threadIdx.x == 0)
        p[blockIdx.x] = red[0] + red[1] + red[2] + red[3];
}

// Phase B: exclusive scan of partials. grid = (1, 2).
__global__ __launch_bounds__(256) void scan_partials_kernel(int* __restrict__ partials, int nb) {
    __shared__ int s[SCAN_B];
    int* p = partials + (long)blockIdx.y * SCAN_NB;
    const int t = threadIdx.x;
    s[t] = (t < nb) ? p[t] : 0;
    __syncthreads();
    for (int off = 1; off < SCAN_B; off <<= 1) {
        int v = (t >= off) ? s[t - off] : 0;
        __syncthreads();
        s[t] += v;
        __syncthreads();
    }
    if (t < nb) p[t] = (t == 0) ? 0 : s[t - 1];  // exclusive
}

// Phase C: per-block exclusive scan + offset -> rowptr (stride n+1). grid = (SCAN_NB, 2).
__global__ __launch_bounds__(256) void scan_final_kernel(const int* __restrict__ deg,
                                                         const int* __restrict__ partials,
                                                         int* __restrict__ rowptr, int n) {
    __shared__ int s[SCAN_B];
    const int* d = deg + (long)blockIdx.y * n;
    const int* p = partials + (long)blockIdx.y * SCAN_NB;
    int* rp = rowptr + (long)blockIdx.y * (n + 1);
    const int t = threadIdx.x;
    const int idx = blockIdx.x * SCAN_B + t;
    const int v0 = (idx < n) ? d[idx] : 0;
    s[t] = v0;
    __syncthreads();
    for (int off = 1; off < SCAN_B; off <<= 1) {
        int v = (t >= off) ? s[t - off] : 0;
        __syncthreads();
        s[t] += v;
        __syncthreads();
    }
    const int excl = p[blockIdx.x] + s[t] - v0;
    if (idx < n) {
        rp[idx] = excl;
        if (idx == n - 1) rp[n] = excl + v0;
    }
}

// Fill both CSRs; (col,val) interleaved as int2.
__global__ void fill2_kernel(const int* __restrict__ row0, const int* __restrict__ col0,
                             const float* __restrict__ val0,
                             const int* __restrict__ row1, const int* __restrict__ col1,
                             const float* __restrict__ val1,
                             const int* __restrict__ rowptr, int* __restrict__ fillc,
                             int2* __restrict__ cv0, int2* __restrict__ cv1, int E, int n) {
    int tid = blockIdx.x * blockDim.x + threadIdx.x;
    if (tid < E) {
        int r = row0[tid];
        int pos = rowptr[r] + atomicAdd(&fillc[r], 1);
        cv0[pos] = make_int2(col0[tid], __float_as_int(val0[tid]));
    } else if (tid < 2 * E) {
        int t = tid - E;
        int r = row1[t];
        int pos = rowptr[(n + 1) + r] + atomicAdd(&fillc[n + r], 1);
        cv1[pos] = make_int2(col1[t], __float_as_int(val1[t]));
    }
}

// ---------------- CSR SpMM: out[r] = bias + sum_e val[e] * sup[col[e]] -------
// One wave per row; sup is fp16, accumulate fp32. F = 64*VEC.
template<int F, int VEC, bool OUT_HALF>
__global__ __launch_bounds__(256) void spmm_kernel(const int* __restrict__ rowptr,
                                                   const int2* __restrict__ cv,
                                                   const __half* __restrict__ sup,
                                                   const float* __restrict__ bias,
                                                   void* __restrict__ outv, int n) {
    static_assert(F == 64 * VEC, "one wave per row");
    const int wave = threadIdx.x >> 6;
    const int lane = threadIdx.x & 63;
    const int r = blockIdx.x * 4 + wave;
    if (r >= n) return;
    const int start = rowptr[r];
    const int end   = rowptr[r + 1];
    const int f0 = lane * VEC;
    float acc0 = bias[f0];
    float acc1 = (VEC == 2) ? bias[f0 + 1] : 0.f;
    for (int e = start; e < end; ++e) {
        const int2 c = cv[e];
        const float v = __int_as_float(c.y);
        if constexpr (VEC == 2) {
            __half2 s = *(const __half2*)(sup + (long)c.x * F + f0);
            float2 sf = __half22float2(s);
            acc0 += v * sf.x;
            acc1 += v * sf.y;
        } else {
            acc0 += v * __half2float(sup[(long)c.x * F + f0]);
        }
    }
    if constexpr (OUT_HALF) {
        __half* out = (__half*)outv;
        if constexpr (VEC == 2)
            *(__half2*)(out + (long)r * F + f0) = __floats2half2_rn(acc0, acc1);
        else
            out[(long)r * F + f0] = __float2half(acc0);
    } else {
        float* out = (float*)outv;
        out[(long)r * F + f0] = acc0;  // VEC==1 path (final layer)
    }
}

extern "C" void kernel_launch(void* const* d_in, const int* in_sizes, int n_in,
                              void* d_out, int out_size, void* d_ws, size_t ws_size,
                              hipStream_t stream) {
    const float* x    = (const float*)d_in[0];
    const int*   row0 = (const int*)d_in[1];
    const int*   col0 = (const int*)d_in[2];
    const float* val0 = (const float*)d_in[3];
    const int*   row1 = (const int*)d_in[4];
    const int*   col1 = (const int*)d_in[5];
    const float* val1 = (const float*)d_in[6];
    const float* W0   = (const float*)d_in[7];
    const float* b0   = (const float*)d_in[8];
    const float* W1   = (const float*)d_in[9];
    const float* b1   = (const float*)d_in[10];
    float* out = (float*)d_out;

    const int M = N_NODES;

    // Workspace layout (all offsets 8B-aligned):
    //   sup0: N*128 fp16 (12.8 MB)  -- reused as sup1 (N*64 fp16)
    //   h:    N*128 fp16 (12.8 MB)
    //   rowptr: 2*(N+1) int  (graph0 then graph1)
    //   deg:    2*N int      (deg0, deg1)
    //   fillc:  2*N int
    //   partials: 2*SCAN_NB int
    //   cv0: E int2 (6.4 MB), cv1: E int2 (6.4 MB)
    __half* sup0   = (__half*)d_ws;
    __half* h      = sup0 + (long)N_NODES * HID_F;
    int* rowptr    = (int*)(h + (long)N_NODES * HID_F);
    int* deg       = rowptr + 2 * (N_NODES + 1);
    int* fillc     = deg + 2 * N_NODES;
    int* partials  = fillc + 2 * N_NODES;
    int2* cv0      = (int2*)(partials + 2 * SCAN_NB);
    int2* cv1      = cv0 + E_EDGES;
    __half* sup1   = sup0;  // sup0 dead after spmm0

    int* rowptr1 = rowptr + (N_NODES + 1);

    const int EB2 = (2 * E_EDGES + 255) / 256;
    const int SPMM_B = (N_NODES + 3) / 4;

    // ---- CSR build for both graphs ----
    zero_int_kernel<<<(4 * N_NODES + 255) / 256, 256, 0, stream>>>(deg, 4 * N_NODES);
    hist2_kernel<<<EB2, 256, 0, stream>>>(row0, row1, deg, E_EDGES, N_NODES);
    scan_sum_kernel<<<dim3(SCAN_NB, 2), SCAN_B, 0, stream>>>(deg, partials, N_NODES);
    scan_partials_kernel<<<dim3(1, 2), SCAN_B, 0, stream>>>(partials, SCAN_NB);
    scan_final_kernel<<<dim3(SCAN_NB, 2), SCAN_B, 0, stream>>>(deg, partials, rowptr, N_NODES);
    fill2_kernel<<<EB2, 256, 0, stream>>>(row0, col0, val0, row1, col1, val1,
                                          rowptr, fillc, cv0, cv1, E_EDGES, N_NODES);

    // ---- Layer 0 ----
    {
        dim3 grid(HID_F / 64, (M + 63) / 64);
        gemm64_kernel<IN_F, HID_F, false, float><<<grid, 256, 0, stream>>>(x, W0, sup0, M);
    }
    spmm_kernel<HID_F, 2, true><<<SPMM_B, 256, 0, stream>>>(rowptr, cv0, sup0, b0, h, N_NODES);

    // ---- Layer 1 ----
    {
        dim3 grid(OUT_F / 64, (M + 63) / 64);
        gemm64_kernel<HID_F, OUT_F, true, __half><<<grid, 256, 0, stream>>>(h, W1, sup1, M);
    }
    spmm_kernel<OUT_F, 1, false><<<SPMM_B, 256, 0, stream>>>(rowptr1, cv1, sup1, b1, out, N_NODES);
}